// Round 1
// baseline (468.701 us; speedup 1.0000x reference)
//
#include <hip/hip_runtime.h>

// SWA non-overlapping window MHA, MI355X gfx950.
// B=8, S=4096, D=512, W=128, H=8, hd=64 -> 256 independent windows.
// Pipeline: [convert weights to bf16] -> [fused QKV+attn per window -> ctx bf16]
//           -> [out-proj GEMM + bias -> fp32 out]

typedef __bf16 bf16x8 __attribute__((ext_vector_type(8)));
typedef float  f32x4  __attribute__((ext_vector_type(4)));

#define MFMA16(a, b, c) __builtin_amdgcn_mfma_f32_16x16x32_bf16((a), (b), (c), 0, 0, 0)

// ---------------- weight conversion ----------------
__global__ void convert_weights_k(const float* __restrict__ w_in,
                                  const float* __restrict__ w_out,
                                  __bf16* __restrict__ w_in_bf,
                                  __bf16* __restrict__ w_out_bf)
{
    int i = blockIdx.x * blockDim.x + threadIdx.x;
    int stride = gridDim.x * blockDim.x;
    for (int j = i; j < 1536 * 512; j += stride) w_in_bf[j]  = (__bf16)w_in[j];
    for (int j = i; j < 512 * 512;  j += stride) w_out_bf[j] = (__bf16)w_out[j];
}

// ---------------- fused QKV + windowed attention ----------------
// grid = 256 (one block per window), block = 512 (8 waves, wave w owns rows 16w..16w+15)
__global__ __launch_bounds__(512, 2)
void swa_qkv_attn(const float* __restrict__ x,
                  const __bf16* __restrict__ w_in,     // [1536][512] row-major bf16
                  const float* __restrict__ b_in,      // [1536]
                  __bf16* __restrict__ ctx)            // [32768][512] bf16
{
    // LDS: padded pitches to dodge bank conflicts on ds_read_b128
    __shared__ __align__(16) __bf16 q_lds[128][72];
    __shared__ __align__(16) __bf16 k_lds[128][72];
    __shared__ __align__(16) __bf16 vT_lds[64][136];    // [d][t] transposed V
    __shared__ __align__(16) __bf16 p_lds[8][16][136];  // per-wave P rows

    const int tid  = threadIdx.x;
    const int w    = tid >> 6;        // wave 0..7
    const int lane = tid & 63;
    const int lrow = lane & 15;
    const int lk   = lane >> 4;       // 0..3
    const long base = (long)blockIdx.x * 128;  // first token row of this window

    // Preload this wave's x fragments (16 rows x 512 cols), cvt fp32->bf16 once.
    // a-frag layout for 16x16x32: lane l holds A[l&15][8*(l>>4) + e], e=0..7
    bf16x8 af[16];
    {
        const float* xr = x + (size_t)(base + 16 * w + lrow) * 512;
        #pragma unroll
        for (int kt = 0; kt < 16; ++kt) {
            const float4* p4 = reinterpret_cast<const float4*>(xr + kt * 32 + 8 * lk);
            float4 f0 = p4[0];
            float4 f1 = p4[1];
            bf16x8 a;
            a[0] = (__bf16)f0.x; a[1] = (__bf16)f0.y; a[2] = (__bf16)f0.z; a[3] = (__bf16)f0.w;
            a[4] = (__bf16)f1.x; a[5] = (__bf16)f1.y; a[6] = (__bf16)f1.z; a[7] = (__bf16)f1.w;
            af[kt] = a;
        }
    }

    for (int h = 0; h < 8; ++h) {
        __syncthreads();   // previous head's LDS consumers are done

        // ---- QKV projection for head h: rows (wave's 16) x 64 cols each of q,k,v ----
        f32x4 accq[4], acck[4], accv[4];
        #pragma unroll
        for (int ct = 0; ct < 4; ++ct) {
            accq[ct] = (f32x4){0.f, 0.f, 0.f, 0.f};
            acck[ct] = (f32x4){0.f, 0.f, 0.f, 0.f};
            accv[ct] = (f32x4){0.f, 0.f, 0.f, 0.f};
        }
        #pragma unroll
        for (int kt = 0; kt < 16; ++kt) {
            bf16x8 a = af[kt];
            #pragma unroll
            for (int ct = 0; ct < 4; ++ct) {
                // b-frag: B[k][n] = W[e][d]; lane: e = e0 + (l&15), d = k0 + 8*(l>>4)..+7
                const __bf16* wp = w_in + (size_t)(64 * h + 16 * ct + lrow) * 512 + kt * 32 + 8 * lk;
                bf16x8 bq = *reinterpret_cast<const bf16x8*>(wp);
                bf16x8 bk = *reinterpret_cast<const bf16x8*>(wp + (size_t)512 * 512);
                bf16x8 bv = *reinterpret_cast<const bf16x8*>(wp + (size_t)1024 * 512);
                accq[ct] = MFMA16(a, bq, accq[ct]);
                acck[ct] = MFMA16(a, bk, acck[ct]);
                accv[ct] = MFMA16(a, bv, accv[ct]);
            }
        }
        // epilogue: bias (+ q scale 1/sqrt(64)), write q,k,vT to LDS as bf16
        #pragma unroll
        for (int ct = 0; ct < 4; ++ct) {
            int e = 64 * h + 16 * ct + lrow;
            float bq = b_in[e], bk = b_in[512 + e], bv = b_in[1024 + e];
            #pragma unroll
            for (int r = 0; r < 4; ++r) {
                int row = 16 * w + 4 * lk + r;          // window-local token
                int d   = 16 * ct + lrow;               // head-local dim
                q_lds[row][d]  = (__bf16)((accq[ct][r] + bq) * 0.125f);
                k_lds[row][d]  = (__bf16)(acck[ct][r] + bk);
                vT_lds[d][row] = (__bf16)(accv[ct][r] + bv);
            }
        }
        __syncthreads();   // q,k,v visible to all waves

        // ---- scores: s[wave's 16 rows][128] = q @ k^T ----
        f32x4 accs[8];
        #pragma unroll
        for (int ct = 0; ct < 8; ++ct) accs[ct] = (f32x4){0.f, 0.f, 0.f, 0.f};
        #pragma unroll
        for (int kt = 0; kt < 2; ++kt) {
            bf16x8 a = *reinterpret_cast<const bf16x8*>(&q_lds[16 * w + lrow][32 * kt + 8 * lk]);
            #pragma unroll
            for (int ct = 0; ct < 8; ++ct) {
                bf16x8 b = *reinterpret_cast<const bf16x8*>(&k_lds[16 * ct + lrow][32 * kt + 8 * lk]);
                accs[ct] = MFMA16(a, b, accs[ct]);
            }
        }

        // ---- softmax over 128 cols; row m lives in 16 lanes of group lk, reg r (m = 4*lk + r) ----
        float invsum[4];
        #pragma unroll
        for (int r = 0; r < 4; ++r) {
            float m = accs[0][r];
            #pragma unroll
            for (int ct = 1; ct < 8; ++ct) m = fmaxf(m, accs[ct][r]);
            m = fmaxf(m, __shfl_xor(m, 1));
            m = fmaxf(m, __shfl_xor(m, 2));
            m = fmaxf(m, __shfl_xor(m, 4));
            m = fmaxf(m, __shfl_xor(m, 8));
            float s = 0.f;
            #pragma unroll
            for (int ct = 0; ct < 8; ++ct) {
                float e = __expf(accs[ct][r] - m);
                s += e;
                p_lds[w][4 * lk + r][16 * ct + lrow] = (__bf16)e;
            }
            s += __shfl_xor(s, 1);
            s += __shfl_xor(s, 2);
            s += __shfl_xor(s, 4);
            s += __shfl_xor(s, 8);
            invsum[r] = 1.f / s;
        }
        __syncthreads();   // p and vT ready (also orders same-wave LDS RAW)

        // ---- PV: ctx_h[wave's 16 rows][64] = P @ V ----
        f32x4 accc[4];
        #pragma unroll
        for (int ct = 0; ct < 4; ++ct) accc[ct] = (f32x4){0.f, 0.f, 0.f, 0.f};
        #pragma unroll
        for (int kt = 0; kt < 4; ++kt) {
            bf16x8 a = *reinterpret_cast<const bf16x8*>(&p_lds[w][lrow][32 * kt + 8 * lk]);
            #pragma unroll
            for (int ct = 0; ct < 4; ++ct) {
                bf16x8 b = *reinterpret_cast<const bf16x8*>(&vT_lds[16 * ct + lrow][32 * kt + 8 * lk]);
                accc[ct] = MFMA16(a, b, accc[ct]);
            }
        }
        // epilogue: normalize by row sum, store ctx bf16 (col = h*64 + d)
        #pragma unroll
        for (int ct = 0; ct < 4; ++ct) {
            #pragma unroll
            for (int r = 0; r < 4; ++r) {
                size_t t = (size_t)(base + 16 * w + 4 * lk + r);
                int col = 64 * h + 16 * ct + lrow;
                ctx[t * 512 + col] = (__bf16)(accc[ct][r] * invsum[r]);
            }
        }
    }
}

// ---------------- out projection: out[32768,512] = ctx @ Wout^T + b ----------------
// grid = (256, 4), block = 256 (4 waves). Block tile 128x128, wave tile 32x128, K=512.
__global__ __launch_bounds__(256, 2)
void swa_outproj(const __bf16* __restrict__ ctx,
                 const __bf16* __restrict__ w_out,    // [512][512] bf16 row-major
                 const float* __restrict__ b_out,
                 float* __restrict__ out)
{
    const int tid  = threadIdx.x;
    const int w    = tid >> 6;
    const int lane = tid & 63;
    const int lrow = lane & 15;
    const int lk   = lane >> 4;
    const size_t rowbase = (size_t)blockIdx.x * 128 + 32 * w;
    const int colbase = blockIdx.y * 128;

    f32x4 acc[2][8];
    #pragma unroll
    for (int rt = 0; rt < 2; ++rt)
        #pragma unroll
        for (int ct = 0; ct < 8; ++ct) acc[rt][ct] = (f32x4){0.f, 0.f, 0.f, 0.f};

    #pragma unroll 4
    for (int kt = 0; kt < 16; ++kt) {
        bf16x8 a0 = *reinterpret_cast<const bf16x8*>(ctx + (rowbase + lrow) * 512 + kt * 32 + 8 * lk);
        bf16x8 a1 = *reinterpret_cast<const bf16x8*>(ctx + (rowbase + 16 + lrow) * 512 + kt * 32 + 8 * lk);
        #pragma unroll
        for (int ct = 0; ct < 8; ++ct) {
            bf16x8 b = *reinterpret_cast<const bf16x8*>(
                w_out + (size_t)(colbase + 16 * ct + lrow) * 512 + kt * 32 + 8 * lk);
            acc[0][ct] = MFMA16(a0, b, acc[0][ct]);
            acc[1][ct] = MFMA16(a1, b, acc[1][ct]);
        }
    }

    #pragma unroll
    for (int ct = 0; ct < 8; ++ct) {
        int col = colbase + 16 * ct + lrow;
        float bias = b_out[col];
        #pragma unroll
        for (int rt = 0; rt < 2; ++rt) {
            #pragma unroll
            for (int r = 0; r < 4; ++r) {
                size_t row = rowbase + 16 * rt + 4 * lk + r;
                out[row * 512 + col] = acc[rt][ct][r] + bias;
            }
        }
    }
}

extern "C" void kernel_launch(void* const* d_in, const int* in_sizes, int n_in,
                              void* d_out, int out_size, void* d_ws, size_t ws_size,
                              hipStream_t stream)
{
    const float* x     = (const float*)d_in[0];
    const float* w_in  = (const float*)d_in[1];
    const float* b_in  = (const float*)d_in[2];
    const float* w_out = (const float*)d_in[3];
    const float* b_out = (const float*)d_in[4];
    float* out = (float*)d_out;

    // workspace layout (bytes): w_in_bf [0, 1572864), w_out_bf [1572864, 2097152),
    // ctx bf16 [2097152, 2097152 + 33554432) -> ~35.7 MB total
    char* ws = (char*)d_ws;
    __bf16* w_in_bf  = (__bf16*)(ws);
    __bf16* w_out_bf = (__bf16*)(ws + 1572864);
    __bf16* ctx      = (__bf16*)(ws + 2097152);

    convert_weights_k<<<512, 256, 0, stream>>>(w_in, w_out, w_in_bf, w_out_bf);
    swa_qkv_attn<<<256, 512, 0, stream>>>(x, w_in_bf, b_in, ctx);
    swa_outproj<<<dim3(256, 4), 256, 0, stream>>>(ctx, w_out_bf, b_out, out);
}

// Round 2
// 165.898 us; speedup vs baseline: 2.8252x; 2.8252x over previous
//
#include <hip/hip_runtime.h>

// SWA non-overlapping window MHA, MI355X gfx950.
// B=8, S=4096, D=512, W=128, H=8, hd=64 -> 256 windows, M=32768 tokens.
// K1 convert fp32->bf16 (x, w_in, w_out)
// K2 QKV GEMM  [32768x1536x512] -> qk (d_out scratch, bf16 [M][1024]) + vT (ws)
// K3 attention per (window, head), no barriers -> ctx bf16 [M][512]
// K4 out-proj GEMM [32768x512x512] + bias -> fp32 d_out

typedef __bf16 bf16x8 __attribute__((ext_vector_type(8)));
typedef __bf16 bf16x4 __attribute__((ext_vector_type(4)));
typedef float  f32x4  __attribute__((ext_vector_type(4)));

#define MFMA16(a, b, c) __builtin_amdgcn_mfma_f32_16x16x32_bf16((a), (b), (c), 0, 0, 0)

__device__ __forceinline__ void gload_lds16(const __bf16* g, void* l) {
    __builtin_amdgcn_global_load_lds(
        (const __attribute__((address_space(1))) unsigned int*)g,
        (__attribute__((address_space(3))) unsigned int*)l, 16, 0, 0);
}

// ---------------- K1: fp32 -> bf16 conversion ----------------
__device__ __forceinline__ void cvt8(const float* __restrict__ s,
                                     __bf16* __restrict__ d, long i) {
    const float4* s4 = reinterpret_cast<const float4*>(s);
    float4 a = s4[2 * i], b = s4[2 * i + 1];
    bf16x8 v;
    v[0] = (__bf16)a.x; v[1] = (__bf16)a.y; v[2] = (__bf16)a.z; v[3] = (__bf16)a.w;
    v[4] = (__bf16)b.x; v[5] = (__bf16)b.y; v[6] = (__bf16)b.z; v[7] = (__bf16)b.w;
    *reinterpret_cast<bf16x8*>(d + 8 * i) = v;
}

__global__ void convert_k(const float* __restrict__ x,
                          const float* __restrict__ w_in,
                          const float* __restrict__ w_out,
                          __bf16* __restrict__ x_bf,
                          __bf16* __restrict__ w_in_bf,
                          __bf16* __restrict__ w_out_bf)
{
    long i0 = (long)blockIdx.x * blockDim.x + threadIdx.x;
    long stride = (long)gridDim.x * blockDim.x;
    for (long i = i0; i < 16777216 / 8; i += stride) cvt8(x, x_bf, i);
    for (long i = i0; i < 786432 / 8;   i += stride) cvt8(w_in, w_in_bf, i);
    for (long i = i0; i < 262144 / 8;   i += stride) cvt8(w_out, w_out_bf, i);
}

// ---------------- K2/K4: 128x128-tile GEMM, K=512, m97-style ----------------
// A [M][512] bf16 row-major, Bw [N][512] bf16 row-major (out col e = Bw row e).
// EPI 0: qkv epilogue (bias, q-scale, v stored transposed). EPI 1: fp32 + bias.
template<int EPI, int NN>
__global__ __launch_bounds__(256)
void gemm128(const __bf16* __restrict__ A,
             const __bf16* __restrict__ Bw,
             const float* __restrict__ bias,
             void* __restrict__ Cq,
             __bf16* __restrict__ vT)
{
    __shared__ __bf16 Al[8192];   // [128 rows][64 k] bf16, 16B-slot XOR swizzled
    __shared__ __bf16 Bl[8192];

    const int nwg = gridDim.x;
    const int chunk = nwg >> 3;                       // nwg % 8 == 0
    const int bid = blockIdx.x;
    const int wg = (bid & 7) * chunk + (bid >> 3);    // XCD-contiguous chunks
    const int nidx = wg % NN;
    const int midx = wg / NN;
    const long mbase = (long)midx * 128;
    const int colbase = nidx * 128;

    const int tid = threadIdx.x;
    const int w = tid >> 6, lane = tid & 63;
    const int lrow = lane & 15, hi = lane >> 4;
    const int srow = lane >> 3, sslot = lane & 7;
    const int sswz = sslot ^ (srow & 7);              // pre-swizzled source slot

    const __bf16* Ag = A + (mbase + w * 32 + srow) * 512 + sswz * 8;
    const __bf16* Bg = Bw + ((long)colbase + w * 32 + srow) * 512 + sswz * 8;
    char* Alc = (char*)Al + w * 4096;
    char* Blc = (char*)Bl + w * 4096;

    const int wm = w >> 1, wn = w & 1;                // 64x64 wave sub-tile

    f32x4 acc[4][4];
    #pragma unroll
    for (int rt = 0; rt < 4; ++rt)
        #pragma unroll
        for (int ct = 0; ct < 4; ++ct) acc[rt][ct] = (f32x4){0.f, 0.f, 0.f, 0.f};

    for (int k0 = 0; k0 < 512; k0 += 64) {
        #pragma unroll
        for (int i = 0; i < 4; ++i) {
            gload_lds16(Ag + (i * 8) * 512 + k0, Alc + i * 1024);
            gload_lds16(Bg + (i * 8) * 512 + k0, Blc + i * 1024);
        }
        __syncthreads();
        #pragma unroll
        for (int ks = 0; ks < 2; ++ks) {
            bf16x8 af[4], bfr[4];
            #pragma unroll
            for (int rt = 0; rt < 4; ++rt) {
                int row = 64 * wm + 16 * rt + lrow;
                af[rt] = *reinterpret_cast<const bf16x8*>(
                    (const char*)Al + row * 128 + ((ks * 64 + hi * 16) ^ ((row & 7) << 4)));
            }
            #pragma unroll
            for (int ct = 0; ct < 4; ++ct) {
                int row = 64 * wn + 16 * ct + lrow;
                bfr[ct] = *reinterpret_cast<const bf16x8*>(
                    (const char*)Bl + row * 128 + ((ks * 64 + hi * 16) ^ ((row & 7) << 4)));
            }
            #pragma unroll
            for (int rt = 0; rt < 4; ++rt)
                #pragma unroll
                for (int ct = 0; ct < 4; ++ct)
                    acc[rt][ct] = MFMA16(af[rt], bfr[ct], acc[rt][ct]);
        }
        __syncthreads();
    }

    if (EPI == 0) {
        const int region = colbase >> 9;              // 0=q, 1=k, 2=v
        if (region < 2) {
            __bf16* qk = (__bf16*)Cq;                 // [M][1024]
            const float scale = (region == 0) ? 0.125f : 1.0f;
            #pragma unroll
            for (int ct = 0; ct < 4; ++ct) {
                int colg = colbase + 64 * wn + 16 * ct + lrow;
                float b = bias[colg];
                #pragma unroll
                for (int rt = 0; rt < 4; ++rt) {
                    long row = mbase + 64 * wm + 16 * rt + 4 * hi;
                    #pragma unroll
                    for (int r = 0; r < 4; ++r)
                        qk[(row + r) * 1024 + colg] = (__bf16)((acc[rt][ct][r] + b) * scale);
                }
            }
        } else {
            // v: store transposed vT[win][h][d][tok], 4 consecutive toks packed
            #pragma unroll
            for (int ct = 0; ct < 4; ++ct) {
                int colg = colbase + 64 * wn + 16 * ct + lrow;
                float b = bias[colg];
                int e2 = colg - 1024;
                int h = e2 >> 6, d = e2 & 63;
                #pragma unroll
                for (int rt = 0; rt < 4; ++rt) {
                    int tok0 = 64 * wm + 16 * rt + 4 * hi;
                    bf16x4 pk;
                    pk[0] = (__bf16)(acc[rt][ct][0] + b);
                    pk[1] = (__bf16)(acc[rt][ct][1] + b);
                    pk[2] = (__bf16)(acc[rt][ct][2] + b);
                    pk[3] = (__bf16)(acc[rt][ct][3] + b);
                    *reinterpret_cast<bf16x4*>(
                        vT + (((long)midx * 8 + h) * 64 + d) * 128 + tok0) = pk;
                }
            }
        }
    } else {
        float* out = (float*)Cq;                      // [M][512] fp32
        #pragma unroll
        for (int ct = 0; ct < 4; ++ct) {
            int colg = colbase + 64 * wn + 16 * ct + lrow;
            float b = bias[colg];
            #pragma unroll
            for (int rt = 0; rt < 4; ++rt) {
                long row = mbase + 64 * wm + 16 * rt + 4 * hi;
                #pragma unroll
                for (int r = 0; r < 4; ++r)
                    out[(row + r) * 512 + colg] = acc[rt][ct][r] + b;
            }
        }
    }
}

// ---------------- K3: attention per (window, head), no barriers ----------------
// grid = 2048 (win*8 + h), block = 256 (4 waves; wave w owns q rows 32w..32w+31)
__global__ __launch_bounds__(256)
void swa_attn(const __bf16* __restrict__ qk,   // [32768][1024]  q cols 0-511 (scaled), k cols 512-1023
              const __bf16* __restrict__ vT,   // [256][8][64][128]
              __bf16* __restrict__ ctx)        // [32768][512]
{
    __shared__ __bf16 p_lds[4][32][136];

    const int bid = blockIdx.x;
    const int win = bid >> 3, h = bid & 7;
    const int tid = threadIdx.x;
    const int w = tid >> 6, lane = tid & 63;
    const int lrow = lane & 15, hi = lane >> 4;
    const long tokb = (long)win * 128;

    // q a-frags for this wave's 32 rows (2 row-frags x 2 k-slices)
    bf16x8 qa[2][2];
    #pragma unroll
    for (int rt = 0; rt < 2; ++rt)
        #pragma unroll
        for (int ks = 0; ks < 2; ++ks)
            qa[rt][ks] = *reinterpret_cast<const bf16x8*>(
                qk + (tokb + 32 * w + 16 * rt + lrow) * 1024 + h * 64 + ks * 32 + hi * 8);

    // scores s[2][8]: 32 q-rows x 128 k-tokens
    f32x4 s[2][8];
    #pragma unroll
    for (int rt = 0; rt < 2; ++rt)
        #pragma unroll
        for (int ct = 0; ct < 8; ++ct) s[rt][ct] = (f32x4){0.f, 0.f, 0.f, 0.f};
    #pragma unroll
    for (int ks = 0; ks < 2; ++ks) {
        #pragma unroll
        for (int ct = 0; ct < 8; ++ct) {
            bf16x8 kb = *reinterpret_cast<const bf16x8*>(
                qk + (tokb + 16 * ct + lrow) * 1024 + 512 + h * 64 + ks * 32 + hi * 8);
            s[0][ct] = MFMA16(qa[0][ks], kb, s[0][ct]);
            s[1][ct] = MFMA16(qa[1][ks], kb, s[1][ct]);
        }
    }

    // softmax per row (row = 16rt + 4hi + r, cols spread over lrow x ct)
    float inv[2][4];
    #pragma unroll
    for (int rt = 0; rt < 2; ++rt) {
        #pragma unroll
        for (int r = 0; r < 4; ++r) {
            float m = s[rt][0][r];
            #pragma unroll
            for (int ct = 1; ct < 8; ++ct) m = fmaxf(m, s[rt][ct][r]);
            m = fmaxf(m, __shfl_xor(m, 1));
            m = fmaxf(m, __shfl_xor(m, 2));
            m = fmaxf(m, __shfl_xor(m, 4));
            m = fmaxf(m, __shfl_xor(m, 8));
            float sum = 0.f;
            #pragma unroll
            for (int ct = 0; ct < 8; ++ct) {
                float e = __expf(s[rt][ct][r] - m);
                sum += e;
                p_lds[w][16 * rt + 4 * hi + r][16 * ct + lrow] = (__bf16)e;
            }
            sum += __shfl_xor(sum, 1);
            sum += __shfl_xor(sum, 2);
            sum += __shfl_xor(sum, 4);
            sum += __shfl_xor(sum, 8);
            inv[rt][r] = 1.f / sum;
        }
    }
    // no barrier: p_lds[w] is wave-private; compiler orders same-wave LDS RAW

    // PV: o[2][4] = P @ V  (b-frag from vT: contiguous tok reads)
    f32x4 o[2][4];
    #pragma unroll
    for (int rt = 0; rt < 2; ++rt)
        #pragma unroll
        for (int ct = 0; ct < 4; ++ct) o[rt][ct] = (f32x4){0.f, 0.f, 0.f, 0.f};
    const __bf16* vb = vT + ((long)win * 8 + h) * 64 * 128;
    #pragma unroll
    for (int kt = 0; kt < 4; ++kt) {
        bf16x8 pa0 = *reinterpret_cast<const bf16x8*>(&p_lds[w][lrow][32 * kt + 8 * hi]);
        bf16x8 pa1 = *reinterpret_cast<const bf16x8*>(&p_lds[w][16 + lrow][32 * kt + 8 * hi]);
        #pragma unroll
        for (int ct = 0; ct < 4; ++ct) {
            bf16x8 vf = *reinterpret_cast<const bf16x8*>(
                vb + (16 * ct + lrow) * 128 + 32 * kt + 8 * hi);
            o[0][ct] = MFMA16(pa0, vf, o[0][ct]);
            o[1][ct] = MFMA16(pa1, vf, o[1][ct]);
        }
    }

    #pragma unroll
    for (int rt = 0; rt < 2; ++rt)
        #pragma unroll
        for (int ct = 0; ct < 4; ++ct)
            #pragma unroll
            for (int r = 0; r < 4; ++r) {
                long tok = tokb + 32 * w + 16 * rt + 4 * hi + r;
                ctx[tok * 512 + h * 64 + 16 * ct + lrow] =
                    (__bf16)(o[rt][ct][r] * inv[rt][r]);
            }
}

extern "C" void kernel_launch(void* const* d_in, const int* in_sizes, int n_in,
                              void* d_out, int out_size, void* d_ws, size_t ws_size,
                              hipStream_t stream)
{
    const float* x     = (const float*)d_in[0];
    const float* w_in  = (const float*)d_in[1];
    const float* b_in  = (const float*)d_in[2];
    const float* w_out = (const float*)d_in[3];
    const float* b_out = (const float*)d_in[4];

    // ws layout (bytes): [x_bf -> later ctx: 0, 33554432) [vT: 33554432, 67108864)
    //                    [w_in_bf: 67108864, +1572864) [w_out_bf: 68681728, +524288)
    // total 69,206,016 B. qk scratch (67.1 MB bf16) lives in d_out until K4.
    char* ws = (char*)d_ws;
    __bf16* x_bf     = (__bf16*)(ws);
    __bf16* ctx      = (__bf16*)(ws);                  // reuses x_bf after K2
    __bf16* vT       = (__bf16*)(ws + 33554432);
    __bf16* w_in_bf  = (__bf16*)(ws + 67108864);
    __bf16* w_out_bf = (__bf16*)(ws + 68681728);
    __bf16* qk       = (__bf16*)d_out;

    convert_k<<<2048, 256, 0, stream>>>(x, w_in, w_out, x_bf, w_in_bf, w_out_bf);
    gemm128<0, 12><<<3072, 256, 0, stream>>>(x_bf, w_in_bf, b_in, (void*)qk, vT);
    swa_attn<<<2048, 256, 0, stream>>>(qk, vT, ctx);
    gemm128<1, 4><<<1024, 256, 0, stream>>>(ctx, w_out_bf, b_out, d_out, nullptr);
}